// Round 1
// baseline (100.911 us; speedup 1.0000x reference)
//
#include <hip/hip_runtime.h>
#include <math.h>

// Closed-form element Hessian for Neo-Hookean energy (MU=LAM=1, Q=1).
// H[a][i][b][k] = vol * ( MU*d_ik*(G[a].G[b]) + LAM*g[a][i]*g[b][k]
//                         + (MU - LAM*logJ)*g[a][k]*g[b][i] ),  g = G * Finv
__global__ __launch_bounds__(256) void mech_hess_kernel(
    const float* __restrict__ U,
    const float* __restrict__ shape_grads,
    const float* __restrict__ vols,
    const int*  __restrict__ conns,
    float* __restrict__ out,
    int E)
{
    int e = blockIdx.x * blockDim.x + threadIdx.x;
    if (e >= E) return;

    // --- loads ---
    int4 cc = *reinterpret_cast<const int4*>(conns + (size_t)e * 4);
    int ca0 = cc.x, ca1 = cc.y, ca2 = cc.z, ca3 = cc.w;

    const float4* gp = reinterpret_cast<const float4*>(shape_grads + (size_t)e * 12);
    float4 q0 = gp[0], q1 = gp[1], q2 = gp[2];
    float G[4][3];
    G[0][0]=q0.x; G[0][1]=q0.y; G[0][2]=q0.z;
    G[1][0]=q0.w; G[1][1]=q1.x; G[1][2]=q1.y;
    G[2][0]=q1.z; G[2][1]=q1.w; G[2][2]=q2.x;
    G[3][0]=q2.y; G[3][1]=q2.z; G[3][2]=q2.w;

    float vol = vols[e];

    // --- F = I + sum_a U[conn[a]] outer G[a] ---
    float F[3][3] = {{1.f,0.f,0.f},{0.f,1.f,0.f},{0.f,0.f,1.f}};
    int ca[4] = {ca0, ca1, ca2, ca3};
    #pragma unroll
    for (int a = 0; a < 4; ++a) {
        float u0 = U[(size_t)ca[a]*3 + 0];
        float u1 = U[(size_t)ca[a]*3 + 1];
        float u2 = U[(size_t)ca[a]*3 + 2];
        #pragma unroll
        for (int j = 0; j < 3; ++j) {
            F[0][j] = fmaf(u0, G[a][j], F[0][j]);
            F[1][j] = fmaf(u1, G[a][j], F[1][j]);
            F[2][j] = fmaf(u2, G[a][j], F[2][j]);
        }
    }

    // --- det, inverse, logJ ---
    float c00 = F[1][1]*F[2][2] - F[1][2]*F[2][1];
    float c01 = F[1][2]*F[2][0] - F[1][0]*F[2][2];
    float c02 = F[1][0]*F[2][1] - F[1][1]*F[2][0];
    float det = F[0][0]*c00 + F[0][1]*c01 + F[0][2]*c02;
    float invdet = 1.0f / det;
    float logJ = logf(det);

    float Fi[3][3];
    Fi[0][0] = c00*invdet;
    Fi[1][0] = c01*invdet;
    Fi[2][0] = c02*invdet;
    Fi[0][1] = (F[0][2]*F[2][1]-F[0][1]*F[2][2])*invdet;
    Fi[1][1] = (F[0][0]*F[2][2]-F[0][2]*F[2][0])*invdet;
    Fi[2][1] = (F[0][1]*F[2][0]-F[0][0]*F[2][1])*invdet;
    Fi[0][2] = (F[0][1]*F[1][2]-F[0][2]*F[1][1])*invdet;
    Fi[1][2] = (F[0][2]*F[1][0]-F[0][0]*F[1][2])*invdet;
    Fi[2][2] = (F[0][0]*F[1][1]-F[0][1]*F[1][0])*invdet;

    // --- g[a][i] = sum_j G[a][j] * Fi[j][i] ---
    float g[4][3];
    #pragma unroll
    for (int a = 0; a < 4; ++a)
        #pragma unroll
        for (int i = 0; i < 3; ++i)
            g[a][i] = G[a][0]*Fi[0][i] + G[a][1]*Fi[1][i] + G[a][2]*Fi[2][i];

    // --- dot[a][b] = G[a].G[b] ---
    float dot[4][4];
    #pragma unroll
    for (int a = 0; a < 4; ++a)
        #pragma unroll
        for (int b = 0; b < 4; ++b)
            dot[a][b] = G[a][0]*G[b][0] + G[a][1]*G[b][1] + G[a][2]*G[b][2];

    const float MU = 1.0f, LAM = 1.0f;
    float c1 = vol * MU;
    float c2 = vol * LAM;
    float c3 = vol * (MU - LAM * logJ);

    float* o = out + (size_t)e * 144;
    #pragma unroll
    for (int a = 0; a < 4; ++a) {
        #pragma unroll
        for (int i = 0; i < 3; ++i) {
            float gai = g[a][i];
            float row[12];
            #pragma unroll
            for (int b = 0; b < 4; ++b) {
                #pragma unroll
                for (int k = 0; k < 3; ++k) {
                    float v = c2 * gai * g[b][k] + c3 * g[a][k] * g[b][i];
                    if (i == k) v = fmaf(c1, dot[a][b], v);
                    row[b*3 + k] = v;
                }
            }
            float4* op = reinterpret_cast<float4*>(o + a*36 + i*12);
            op[0] = make_float4(row[0], row[1], row[2],  row[3]);
            op[1] = make_float4(row[4], row[5], row[6],  row[7]);
            op[2] = make_float4(row[8], row[9], row[10], row[11]);
        }
    }
}

extern "C" void kernel_launch(void* const* d_in, const int* in_sizes, int n_in,
                              void* d_out, int out_size, void* d_ws, size_t ws_size,
                              hipStream_t stream) {
    // setup_inputs order: U, coords, state, shapes, shape_grads, vols, conns
    const float* U           = (const float*)d_in[0];
    const float* shape_grads = (const float*)d_in[4];
    const float* vols        = (const float*)d_in[5];
    const int*   conns       = (const int*)d_in[6];
    float* out = (float*)d_out;

    int E = in_sizes[5];  // vols is (E, 1)

    int block = 256;
    int grid = (E + block - 1) / block;
    mech_hess_kernel<<<grid, block, 0, stream>>>(U, shape_grads, vols, conns, out, E);
}

// Round 2
// 34.512 us; speedup vs baseline: 2.9240x; 2.9240x over previous
//
#include <hip/hip_runtime.h>
#include <math.h>

// Closed-form element Hessian for Neo-Hookean energy (MU=LAM=1, Q=1).
// H[a][i][b][k] = vol * ( MU*d_ik*(G[a].G[b]) + LAM*g[a][i]*g[b][k]
//                         + (MU - LAM*logJ)*g[a][k]*g[b][i] ),  g = G * Finv
//
// R1: LDS-staged coalesced output writes. R0 had 3x HBM write amplification
// (576B-strided 16B stores -> partial-line evictions). Now each wave stages
// 16 elements (9216B) in LDS and writes back 1024B-contiguous per store.

struct ElemData {
    float g[4][3];
    float dot[4][4];
    float c1, c2, c3;
};

__device__ __forceinline__ ElemData compute_elem(
    const float* __restrict__ U,
    const float* __restrict__ shape_grads,
    const float* __restrict__ vols,
    const int*  __restrict__ conns,
    size_t e)
{
    ElemData d;
    int4 cc = *reinterpret_cast<const int4*>(conns + e * 4);
    const float4* gp = reinterpret_cast<const float4*>(shape_grads + e * 12);
    float4 q0 = gp[0], q1 = gp[1], q2 = gp[2];
    float G[4][3];
    G[0][0]=q0.x; G[0][1]=q0.y; G[0][2]=q0.z;
    G[1][0]=q0.w; G[1][1]=q1.x; G[1][2]=q1.y;
    G[2][0]=q1.z; G[2][1]=q1.w; G[2][2]=q2.x;
    G[3][0]=q2.y; G[3][1]=q2.z; G[3][2]=q2.w;

    float vol = vols[e];

    float F[3][3] = {{1.f,0.f,0.f},{0.f,1.f,0.f},{0.f,0.f,1.f}};
    int ca[4] = {cc.x, cc.y, cc.z, cc.w};
    #pragma unroll
    for (int a = 0; a < 4; ++a) {
        float u0 = U[(size_t)ca[a]*3 + 0];
        float u1 = U[(size_t)ca[a]*3 + 1];
        float u2 = U[(size_t)ca[a]*3 + 2];
        #pragma unroll
        for (int j = 0; j < 3; ++j) {
            F[0][j] = fmaf(u0, G[a][j], F[0][j]);
            F[1][j] = fmaf(u1, G[a][j], F[1][j]);
            F[2][j] = fmaf(u2, G[a][j], F[2][j]);
        }
    }

    float c00 = F[1][1]*F[2][2] - F[1][2]*F[2][1];
    float c01 = F[1][2]*F[2][0] - F[1][0]*F[2][2];
    float c02 = F[1][0]*F[2][1] - F[1][1]*F[2][0];
    float det = F[0][0]*c00 + F[0][1]*c01 + F[0][2]*c02;
    float invdet = 1.0f / det;
    float logJ = logf(det);

    float Fi[3][3];
    Fi[0][0] = c00*invdet;
    Fi[1][0] = c01*invdet;
    Fi[2][0] = c02*invdet;
    Fi[0][1] = (F[0][2]*F[2][1]-F[0][1]*F[2][2])*invdet;
    Fi[1][1] = (F[0][0]*F[2][2]-F[0][2]*F[2][0])*invdet;
    Fi[2][1] = (F[0][1]*F[2][0]-F[0][0]*F[2][1])*invdet;
    Fi[0][2] = (F[0][1]*F[1][2]-F[0][2]*F[1][1])*invdet;
    Fi[1][2] = (F[0][2]*F[1][0]-F[0][0]*F[1][2])*invdet;
    Fi[2][2] = (F[0][0]*F[1][1]-F[0][1]*F[1][0])*invdet;

    #pragma unroll
    for (int a = 0; a < 4; ++a)
        #pragma unroll
        for (int i = 0; i < 3; ++i)
            d.g[a][i] = G[a][0]*Fi[0][i] + G[a][1]*Fi[1][i] + G[a][2]*Fi[2][i];

    #pragma unroll
    for (int a = 0; a < 4; ++a)
        #pragma unroll
        for (int b = 0; b < 4; ++b)
            d.dot[a][b] = G[a][0]*G[b][0] + G[a][1]*G[b][1] + G[a][2]*G[b][2];

    const float MUc = 1.0f, LAMc = 1.0f;
    d.c1 = vol * MUc;
    d.c2 = vol * LAMc;
    d.c3 = vol * (MUc - LAMc * logJ);
    return d;
}

__device__ __forceinline__ void make_row(const ElemData& d, int a, int i,
                                         float4& r0, float4& r1, float4& r2)
{
    float row[12];
    float gai = d.g[a][i];
    #pragma unroll
    for (int b = 0; b < 4; ++b) {
        #pragma unroll
        for (int k = 0; k < 3; ++k) {
            float v = d.c2 * gai * d.g[b][k] + d.c3 * d.g[a][k] * d.g[b][i];
            if (i == k) v = fmaf(d.c1, d.dot[a][b], v);
            row[b*3 + k] = v;
        }
    }
    r0 = make_float4(row[0], row[1], row[2],  row[3]);
    r1 = make_float4(row[4], row[5], row[6],  row[7]);
    r2 = make_float4(row[8], row[9], row[10], row[11]);
}

__global__ __launch_bounds__(256) void mech_hess_kernel(
    const float* __restrict__ U,
    const float* __restrict__ shape_grads,
    const float* __restrict__ vols,
    const int*  __restrict__ conns,
    float* __restrict__ out,
    int E)
{
    // per-wave staging: 16 elems x 37 float4 slots (36 data + 1 pad)
    __shared__ float4 buf[4][16 * 37];

    int tid  = threadIdx.x;
    int wave = tid >> 6;
    int lane = tid & 63;
    size_t e = (size_t)blockIdx.x * 256 + tid;

    bool fullBlock = ((size_t)blockIdx.x * 256 + 256) <= (size_t)E;

    if (fullBlock) {
        ElemData d = compute_elem(U, shape_grads, vols, conns, e);
        float4* ob = reinterpret_cast<float4*>(out);

        #pragma unroll
        for (int c = 0; c < 4; ++c) {
            if ((lane >> 4) == c) {
                int m = lane & 15;
                float4* wb = &buf[wave][m * 37];
                #pragma unroll
                for (int a = 0; a < 4; ++a) {
                    #pragma unroll
                    for (int i = 0; i < 3; ++i) {
                        float4 r0, r1, r2;
                        make_row(d, a, i, r0, r1, r2);
                        int j = (a*3 + i) * 3;
                        wb[j+0] = r0; wb[j+1] = r1; wb[j+2] = r2;
                    }
                }
            }
            __syncthreads();
            // coalesced write-out: 16 elems * 576B = 9216B = 576 float4
            size_t chunkF4 = ((size_t)blockIdx.x * 256 + wave*64 + c*16) * 36;
            #pragma unroll
            for (int it = 0; it < 9; ++it) {
                int s = it*64 + lane;          // 0..575
                int elem = s / 36;             // compile-time magic div
                int slot = s + elem;           // elem*37 + (s - elem*36)
                ob[chunkF4 + s] = buf[wave][slot];
            }
            __syncthreads();
        }
    } else {
        if (e < (size_t)E) {
            ElemData d = compute_elem(U, shape_grads, vols, conns, e);
            float* o = out + e * 144;
            #pragma unroll
            for (int a = 0; a < 4; ++a) {
                #pragma unroll
                for (int i = 0; i < 3; ++i) {
                    float4 r0, r1, r2;
                    make_row(d, a, i, r0, r1, r2);
                    float4* op = reinterpret_cast<float4*>(o + a*36 + i*12);
                    op[0] = r0; op[1] = r1; op[2] = r2;
                }
            }
        }
    }
}

extern "C" void kernel_launch(void* const* d_in, const int* in_sizes, int n_in,
                              void* d_out, int out_size, void* d_ws, size_t ws_size,
                              hipStream_t stream) {
    // setup_inputs order: U, coords, state, shapes, shape_grads, vols, conns
    const float* U           = (const float*)d_in[0];
    const float* shape_grads = (const float*)d_in[4];
    const float* vols        = (const float*)d_in[5];
    const int*   conns       = (const int*)d_in[6];
    float* out = (float*)d_out;

    int E = in_sizes[5];  // vols is (E, 1)

    int block = 256;
    int grid = (E + block - 1) / block;
    mech_hess_kernel<<<grid, block, 0, stream>>>(U, shape_grads, vols, conns, out, E);
}

// Round 3
// 33.975 us; speedup vs baseline: 2.9702x; 1.0158x over previous
//
#include <hip/hip_runtime.h>
#include <math.h>

// Closed-form element Hessian for Neo-Hookean energy (MU=LAM=1, Q=1).
// H[a][i][b][k] = vol * ( MU*d_ik*(G[a].G[b]) + LAM*g[a][i]*g[b][k]
//                         + (MU - LAM*logJ)*g[a][k]*g[b][i] ),  g = G * Finv
//
// R1: LDS-staged coalesced output writes (fixed 3x HBM write amplification).
// R2: wave-private staging needs NO runtime barrier. Replaced the 8 block-wide
//     __syncthreads (which coupled all 4 waves at every phase boundary and put
//     bubbles in the store stream) with compile-time scheduling fences.
//     LDS ops within a wave execute in order; fences only stop compiler reorder.

struct ElemData {
    float g[4][3];
    float dot[4][4];
    float c1, c2, c3;
};

__device__ __forceinline__ ElemData compute_elem(
    const float* __restrict__ U,
    const float* __restrict__ shape_grads,
    const float* __restrict__ vols,
    const int*  __restrict__ conns,
    size_t e)
{
    ElemData d;
    int4 cc = *reinterpret_cast<const int4*>(conns + e * 4);
    const float4* gp = reinterpret_cast<const float4*>(shape_grads + e * 12);
    float4 q0 = gp[0], q1 = gp[1], q2 = gp[2];
    float G[4][3];
    G[0][0]=q0.x; G[0][1]=q0.y; G[0][2]=q0.z;
    G[1][0]=q0.w; G[1][1]=q1.x; G[1][2]=q1.y;
    G[2][0]=q1.z; G[2][1]=q1.w; G[2][2]=q2.x;
    G[3][0]=q2.y; G[3][1]=q2.z; G[3][2]=q2.w;

    float vol = vols[e];

    float F[3][3] = {{1.f,0.f,0.f},{0.f,1.f,0.f},{0.f,0.f,1.f}};
    int ca[4] = {cc.x, cc.y, cc.z, cc.w};
    #pragma unroll
    for (int a = 0; a < 4; ++a) {
        float u0 = U[(size_t)ca[a]*3 + 0];
        float u1 = U[(size_t)ca[a]*3 + 1];
        float u2 = U[(size_t)ca[a]*3 + 2];
        #pragma unroll
        for (int j = 0; j < 3; ++j) {
            F[0][j] = fmaf(u0, G[a][j], F[0][j]);
            F[1][j] = fmaf(u1, G[a][j], F[1][j]);
            F[2][j] = fmaf(u2, G[a][j], F[2][j]);
        }
    }

    float c00 = F[1][1]*F[2][2] - F[1][2]*F[2][1];
    float c01 = F[1][2]*F[2][0] - F[1][0]*F[2][2];
    float c02 = F[1][0]*F[2][1] - F[1][1]*F[2][0];
    float det = F[0][0]*c00 + F[0][1]*c01 + F[0][2]*c02;
    float invdet = 1.0f / det;
    float logJ = logf(det);

    float Fi[3][3];
    Fi[0][0] = c00*invdet;
    Fi[1][0] = c01*invdet;
    Fi[2][0] = c02*invdet;
    Fi[0][1] = (F[0][2]*F[2][1]-F[0][1]*F[2][2])*invdet;
    Fi[1][1] = (F[0][0]*F[2][2]-F[0][2]*F[2][0])*invdet;
    Fi[2][1] = (F[0][1]*F[2][0]-F[0][0]*F[2][1])*invdet;
    Fi[0][2] = (F[0][1]*F[1][2]-F[0][2]*F[1][1])*invdet;
    Fi[1][2] = (F[0][2]*F[1][0]-F[0][0]*F[1][2])*invdet;
    Fi[2][2] = (F[0][0]*F[1][1]-F[0][1]*F[1][0])*invdet;

    #pragma unroll
    for (int a = 0; a < 4; ++a)
        #pragma unroll
        for (int i = 0; i < 3; ++i)
            d.g[a][i] = G[a][0]*Fi[0][i] + G[a][1]*Fi[1][i] + G[a][2]*Fi[2][i];

    #pragma unroll
    for (int a = 0; a < 4; ++a)
        #pragma unroll
        for (int b = 0; b < 4; ++b)
            d.dot[a][b] = G[a][0]*G[b][0] + G[a][1]*G[b][1] + G[a][2]*G[b][2];

    const float MUc = 1.0f, LAMc = 1.0f;
    d.c1 = vol * MUc;
    d.c2 = vol * LAMc;
    d.c3 = vol * (MUc - LAMc * logJ);
    return d;
}

__device__ __forceinline__ void make_row(const ElemData& d, int a, int i,
                                         float4& r0, float4& r1, float4& r2)
{
    float row[12];
    float gai = d.g[a][i];
    #pragma unroll
    for (int b = 0; b < 4; ++b) {
        #pragma unroll
        for (int k = 0; k < 3; ++k) {
            float v = d.c2 * gai * d.g[b][k] + d.c3 * d.g[a][k] * d.g[b][i];
            if (i == k) v = fmaf(d.c1, d.dot[a][b], v);
            row[b*3 + k] = v;
        }
    }
    r0 = make_float4(row[0], row[1], row[2],  row[3]);
    r1 = make_float4(row[4], row[5], row[6],  row[7]);
    r2 = make_float4(row[8], row[9], row[10], row[11]);
}

__device__ __forceinline__ void lds_fence() {
    // Compile-time only: keep the compiler from reordering LDS ops across
    // phase boundaries. No runtime barrier needed: buf is wave-private and
    // LDS ops within a wave complete in program order.
    __builtin_amdgcn_sched_barrier(0);
    __builtin_amdgcn_wave_barrier();
    __builtin_amdgcn_sched_barrier(0);
}

__global__ __launch_bounds__(256) void mech_hess_kernel(
    const float* __restrict__ U,
    const float* __restrict__ shape_grads,
    const float* __restrict__ vols,
    const int*  __restrict__ conns,
    float* __restrict__ out,
    int E)
{
    // per-wave staging: 16 elems x 37 float4 slots (36 data + 1 pad)
    __shared__ float4 buf[4][16 * 37];

    int tid  = threadIdx.x;
    int wave = tid >> 6;
    int lane = tid & 63;
    size_t e = (size_t)blockIdx.x * 256 + tid;

    bool fullBlock = ((size_t)blockIdx.x * 256 + 256) <= (size_t)E;

    if (fullBlock) {
        ElemData d = compute_elem(U, shape_grads, vols, conns, e);
        float4* ob = reinterpret_cast<float4*>(out);

        #pragma unroll
        for (int c = 0; c < 4; ++c) {
            if ((lane >> 4) == c) {
                int m = lane & 15;
                float4* wb = &buf[wave][m * 37];
                #pragma unroll
                for (int a = 0; a < 4; ++a) {
                    #pragma unroll
                    for (int i = 0; i < 3; ++i) {
                        float4 r0, r1, r2;
                        make_row(d, a, i, r0, r1, r2);
                        int j = (a*3 + i) * 3;
                        wb[j+0] = r0; wb[j+1] = r1; wb[j+2] = r2;
                    }
                }
            }
            lds_fence();
            // coalesced write-out: 16 elems * 576B = 9216B = 576 float4
            size_t chunkF4 = ((size_t)blockIdx.x * 256 + wave*64 + c*16) * 36;
            #pragma unroll
            for (int it = 0; it < 9; ++it) {
                int s = it*64 + lane;          // 0..575
                int elem = s / 36;             // compile-time magic div
                int slot = s + elem;           // elem*37 + (s - elem*36)
                ob[chunkF4 + s] = buf[wave][slot];
            }
            lds_fence();
        }
    } else {
        if (e < (size_t)E) {
            ElemData d = compute_elem(U, shape_grads, vols, conns, e);
            float* o = out + e * 144;
            #pragma unroll
            for (int a = 0; a < 4; ++a) {
                #pragma unroll
                for (int i = 0; i < 3; ++i) {
                    float4 r0, r1, r2;
                    make_row(d, a, i, r0, r1, r2);
                    float4* op = reinterpret_cast<float4*>(o + a*36 + i*12);
                    op[0] = r0; op[1] = r1; op[2] = r2;
                }
            }
        }
    }
}

extern "C" void kernel_launch(void* const* d_in, const int* in_sizes, int n_in,
                              void* d_out, int out_size, void* d_ws, size_t ws_size,
                              hipStream_t stream) {
    // setup_inputs order: U, coords, state, shapes, shape_grads, vols, conns
    const float* U           = (const float*)d_in[0];
    const float* shape_grads = (const float*)d_in[4];
    const float* vols        = (const float*)d_in[5];
    const int*   conns       = (const int*)d_in[6];
    float* out = (float*)d_out;

    int E = in_sizes[5];  // vols is (E, 1)

    int block = 256;
    int grid = (E + block - 1) / block;
    mech_hess_kernel<<<grid, block, 0, stream>>>(U, shape_grads, vols, conns, out, E);
}